// Round 1
// baseline (554.614 us; speedup 1.0000x reference)
//
#include <hip/hip_runtime.h>
#include <hip/hip_bf16.h>

// Problem constants (from reference): V=50000, D=512, H=512, L=4, E=40000
#define NV 50000
#define ND 512
#define NH 512
#define NL 4
#define NE 40000
#define TILE_E 32   // edges per block; NE % TILE_E == 0 (40000/32 = 1250)

typedef short bf16x8 __attribute__((ext_vector_type(8)));  // 8 bf16 in 4 VGPRs (MFMA A/B frag)
typedef float f32x4  __attribute__((ext_vector_type(4)));  // MFMA C/D frag

// f32 -> bf16 round-to-nearest-even (bit trick; avoids hip_bf16 API variance)
__device__ __forceinline__ unsigned short f2bf(float f) {
    unsigned int u = __float_as_uint(f);
    u += 0x7FFFu + ((u >> 16) & 1u);
    return (unsigned short)(u >> 16);
}

// ---------------------------------------------------------------------------
// Kernel 1: Wt[l][h][k] = bf16(W[l][k][h])   (2 MiB output in d_ws)
// Coalesced reads, scattered 2B writes — only 4M elements, trivial cost.
// ---------------------------------------------------------------------------
__global__ void wt_kernel(const float* __restrict__ W, unsigned short* __restrict__ Wt) {
    int idx = blockIdx.x * 256 + threadIdx.x;     // over NL*ND*NH = 4194304
    int l = idx >> 18;                            // ND*NH = 262144 = 2^18
    int r = idx & 262143;
    int k = r >> 9;                               // NH = 512
    int h = r & 511;
    Wt[(l << 18) + (h << 9) + k] = f2bf(W[idx]);
}

// ---------------------------------------------------------------------------
// Kernel 2: per block: gather 32 emb rows -> swizzled LDS (bf16),
// GEMM [32 x 512] x Wt[l] (K=512) via mfma_f32_16x16x32_bf16,
// scatter-add D-fragments into out with f32 atomics.
// Wave w owns H columns [w*128, w*128+128).
// ---------------------------------------------------------------------------
__global__ void __launch_bounds__(256)
msg_kernel(const float* __restrict__ emb,
           const int*   __restrict__ adj,
           const unsigned short* __restrict__ Wt,
           float* __restrict__ out) {
    // A tile: 32 rows x 512 k, bf16, stored as 64 x 16B slots per row.
    // Swizzle: slot' = slot ^ (row & 7)  (spreads the 1KiB row stride across banks)
    __shared__ bf16x8 s_a[TILE_E * 64];
    __shared__ int s_src[TILE_E];
    __shared__ int s_tgt[TILE_E];

    const int bx   = blockIdx.x;
    const int l    = bx / (NE / TILE_E);
    const int tile = bx % (NE / TILE_E);
    const int ebase = tile * TILE_E;
    const int tid  = threadIdx.x;
    const int lane = tid & 63;
    const int wave = tid >> 6;

    if (tid < TILE_E) {
        int2 p = *(const int2*)(adj + ((size_t)l * NE + ebase + tid) * 2);
        s_src[tid] = p.x;
        s_tgt[tid] = p.y;
    }
    __syncthreads();

    // ---- Stage A: 8 threads per row, each thread converts 64 consecutive k ----
    {
        const int r    = tid >> 3;
        const int part = tid & 7;
        const int k0   = part * 64;
        const int rx   = r & 7;
        const float* g = emb + (size_t)s_src[r] * ND + k0;
#pragma unroll
        for (int j = 0; j < 8; ++j) {
            float4 f0 = *(const float4*)(g + j * 8);
            float4 f1 = *(const float4*)(g + j * 8 + 4);
            bf16x8 v;
            v[0] = (short)f2bf(f0.x); v[1] = (short)f2bf(f0.y);
            v[2] = (short)f2bf(f0.z); v[3] = (short)f2bf(f0.w);
            v[4] = (short)f2bf(f1.x); v[5] = (short)f2bf(f1.y);
            v[6] = (short)f2bf(f1.z); v[7] = (short)f2bf(f1.w);
            int slot = (k0 >> 3) + j;
            s_a[r * 64 + (slot ^ rx)] = v;
        }
    }
    __syncthreads();

    // ---- MFMA main loop ----
    const int c0    = wave * 128;          // this wave's H base
    const int laneL = lane & 15;
    const int laneH = lane >> 4;

    f32x4 acc[2][8];
#pragma unroll
    for (int mf = 0; mf < 2; ++mf)
#pragma unroll
        for (int nf = 0; nf < 8; ++nf)
            acc[mf][nf] = (f32x4){0.f, 0.f, 0.f, 0.f};

    const bf16x8* wb = reinterpret_cast<const bf16x8*>(Wt + ((size_t)l << 18));
    const int rx = laneL & 7;  // same for rows laneL and 16+laneL

#pragma unroll
    for (int kc = 0; kc < ND / 32; ++kc) {          // 16 k-chunks of 32
        const int slot = kc * 4 + laneH;            // k = kc*32 + laneH*8 -> 16B slot
        bf16x8 a0 = s_a[laneL * 64        + (slot ^ rx)];
        bf16x8 a1 = s_a[(16 + laneL) * 64 + (slot ^ rx)];
#pragma unroll
        for (int nf = 0; nf < 8; ++nf) {
            int h = c0 + nf * 16 + laneL;
            bf16x8 b = wb[h * 64 + slot];           // Wt[l][h][kc*32 + laneH*8 ..+8]
            acc[0][nf] = __builtin_amdgcn_mfma_f32_16x16x32_bf16(a0, b, acc[0][nf], 0, 0, 0);
            acc[1][nf] = __builtin_amdgcn_mfma_f32_16x16x32_bf16(a1, b, acc[1][nf], 0, 0, 0);
        }
    }

    // ---- Scatter-add epilogue ----
    // D layout (verified m89/m91): col = lane&15, row = (lane>>4)*4 + i
#pragma unroll
    for (int mf = 0; mf < 2; ++mf) {
#pragma unroll
        for (int nf = 0; nf < 8; ++nf) {
            int h = c0 + nf * 16 + laneL;
#pragma unroll
            for (int i = 0; i < 4; ++i) {
                int er = mf * 16 + laneH * 4 + i;
                int t  = s_tgt[er];
                atomicAdd(out + (size_t)t * NH + h, acc[mf][nf][i]);
            }
        }
    }
}

// ---------------------------------------------------------------------------
// Kernel 3: in-place ReLU (float4, grid-stride)
// ---------------------------------------------------------------------------
__global__ void relu_kernel(float* __restrict__ o, int n4) {
    int stride = gridDim.x * blockDim.x;
    for (int i = blockIdx.x * blockDim.x + threadIdx.x; i < n4; i += stride) {
        float4 v = ((float4*)o)[i];
        v.x = fmaxf(v.x, 0.f);
        v.y = fmaxf(v.y, 0.f);
        v.z = fmaxf(v.z, 0.f);
        v.w = fmaxf(v.w, 0.f);
        ((float4*)o)[i] = v;
    }
}

extern "C" void kernel_launch(void* const* d_in, const int* in_sizes, int n_in,
                              void* d_out, int out_size, void* d_ws, size_t ws_size,
                              hipStream_t stream) {
    const float* emb = (const float*)d_in[0];          // [V, D] f32
    const int*   adj = (const int*)d_in[1];            // [L, E, 2] i32
    const float* W   = (const float*)d_in[2];          // [L, D, H] f32
    float* out = (float*)d_out;                        // [V, H] f32
    unsigned short* Wt = (unsigned short*)d_ws;        // [L, H, D] bf16 (2 MiB)

    // zero accumulator (atomics add into it)
    hipMemsetAsync(d_out, 0, (size_t)out_size * sizeof(float), stream);

    wt_kernel<<<(NL * ND * NH) / 256, 256, 0, stream>>>(W, Wt);
    msg_kernel<<<NL * (NE / TILE_E), 256, 0, stream>>>(emb, adj, Wt, out);
    relu_kernel<<<2048, 256, 0, stream>>>(out, out_size / 4);
}